// Round 7
// baseline (231.514 us; speedup 1.0000x reference)
//
#include <hip/hip_runtime.h>

typedef __bf16 bf16;
typedef __bf16 bf16x8 __attribute__((ext_vector_type(8)));
typedef float f32x4 __attribute__((ext_vector_type(4)));

#define DEPTH   18
#define N_NODES ((1 << DEPTH) - 1)      // 262143
#define KDIM    192                     // E + 2H
#define RDIM    320                     // 3H + 2H
#define A_PAD   200                     // padded A-row stride (bf16 elems)
#define LOG2E   1.4426950408889634f

__device__ __forceinline__ float rcpf(float x) { return __builtin_amdgcn_rcpf(x); }
// pre-activations pre-scaled by log2e (folded into Wcat/bias)
__device__ __forceinline__ float sig2(float p)  { return rcpf(1.f + exp2f(-p)); }
__device__ __forceinline__ float tanhf_(float x){ return 2.f * rcpf(1.f + exp2f(-2.f * LOG2E * x)) - 1.f; }

__device__ __forceinline__ bf16x8 as_bf16x8(f32x4 v) {
    union { f32x4 f; bf16x8 b; } u; u.f = v; return u.b;
}

// shared epilogue: acc[5] + biases + children c -> c4, h4
__device__ __forceinline__ void gates(const f32x4* acc,
        const float4& bI, const float4& bO, const float4& bU,
        const float4& bL, const float4& bR,
        const float4& cl, const float4& cr, float4& c4, float4& h4) {
    const float* pbI = &bI.x; const float* pbO = &bO.x; const float* pbU = &bU.x;
    const float* pbL = &bL.x; const float* pbR = &bR.x;
    const float* pcl = &cl.x; const float* pcr = &cr.x;
    float* pc4 = &c4.x; float* ph4 = &h4.x;
#pragma unroll
    for (int r = 0; r < 4; r++) {
        float i_g = sig2(acc[0][r] + pbI[r]);
        float o_g = sig2(acc[1][r] + pbO[r]);
        float u_g = tanhf_(sig2(acc[2][r] + pbU[r]));   // ref: tanh(sigmoid(pre_u))
        float fl  = sig2(acc[3][r] + pbL[r]);
        float fr  = sig2(acc[4][r] + pbR[r]);
        float c = i_g * u_g + fl * pcl[r] + fr * pcr[r];
        pc4[r] = c;
        ph4[r] = o_g * tanhf_(c);
    }
}

// ---- dispatch 1: blocks 0..511 elementwise pack (Wcat, bias, emb16);
// blocks 512..543 leaf tables (independent: convert own W/emb slices). ----
__global__ void prep_all(const float* __restrict__ emb,
                     const float* __restrict__ W_iou, const float* __restrict__ U_iou,
                     const float* __restrict__ W_f,   const float* __restrict__ U_f,
                     const float* __restrict__ b_Wiou, const float* __restrict__ b_Uiou,
                     const float* __restrict__ b_Wf,   const float* __restrict__ b_Uf,
                     bf16* __restrict__ Wcat, float* __restrict__ bias, bf16* __restrict__ emb16,
                     bf16* __restrict__ leafH, float* __restrict__ leafC) {
    __shared__ __align__(16) bf16 Wl[192 * 72];
    __shared__ __align__(16) bf16 Al[64 * 72];
    const int blk = blockIdx.x, tid = threadIdx.x;
    if (blk < 512) {
        int t = blk * 256 + tid;                 // t < 131072 == 2048*64
        emb16[t] = (bf16)emb[t];
        if (t < RDIM * KDIM) {
            int r = t / KDIM, k = t % KDIM;
            float v;
            if (r < 192) v = (k < 64) ? W_iou[r * 64 + k] : U_iou[r * 128 + (k - 64)];
            else { int rr = r - 192; v = (k < 64) ? W_f[rr * 64 + k] : U_f[rr * 128 + (k - 64)]; }
            Wcat[t] = (bf16)(v * LOG2E);
        }
        if (t < RDIM)
            bias[t] = ((t < 192) ? (b_Wiou[t] + b_Uiou[t]) : (b_Wf[t - 192] + b_Uf[t - 192])) * LOG2E;
        return;
    }
    // ---- leaf-table block: vocab slice [v0, v0+64) ----
    const int v0 = (blk - 512) * 64;
    for (int i = tid; i < 192 * 64; i += 256) {
        int r = i >> 6, k = i & 63;
        Wl[r * 72 + k] = (bf16)(W_iou[i] * LOG2E);
    }
    for (int i = tid; i < 64 * 64; i += 256) {
        int r = i >> 6, k = i & 63;
        Al[r * 72 + k] = (bf16)emb[(v0 << 6) + i];
    }
    __syncthreads();
    const int wave = tid >> 6, lane = tid & 63;
    const int l15 = lane & 15, quad = lane >> 4;
    const int jw = (wave & 3) * 16, jb = jw + quad * 4;

    f32x4 acc[4][3];
#pragma unroll
    for (int t = 0; t < 4; t++)
#pragma unroll
        for (int g = 0; g < 3; g++) acc[t][g] = (f32x4){0.f, 0.f, 0.f, 0.f};
#pragma unroll
    for (int kb = 0; kb < 2; kb++) {
        bf16x8 wfrag[3], nfrag[4];
#pragma unroll
        for (int g = 0; g < 3; g++)
            wfrag[g] = *(const bf16x8*)(&Wl[(g * 64 + jw + l15) * 72 + kb * 32 + quad * 8]);
#pragma unroll
        for (int t = 0; t < 4; t++)
            nfrag[t] = *(const bf16x8*)(&Al[(t * 16 + l15) * 72 + kb * 32 + quad * 8]);
#pragma unroll
        for (int t = 0; t < 4; t++)
#pragma unroll
            for (int g = 0; g < 3; g++)
                acc[t][g] = __builtin_amdgcn_mfma_f32_16x16x32_bf16(wfrag[g], nfrag[t], acc[t][g], 0, 0, 0);
    }
    float4 bW, bU_;
    bW = *(const float4*)(b_Wiou + jb);       bU_ = *(const float4*)(b_Uiou + jb);
    float4 bI = make_float4((bW.x + bU_.x) * LOG2E, (bW.y + bU_.y) * LOG2E, (bW.z + bU_.z) * LOG2E, (bW.w + bU_.w) * LOG2E);
    bW = *(const float4*)(b_Wiou + 64 + jb);  bU_ = *(const float4*)(b_Uiou + 64 + jb);
    float4 bO = make_float4((bW.x + bU_.x) * LOG2E, (bW.y + bU_.y) * LOG2E, (bW.z + bU_.z) * LOG2E, (bW.w + bU_.w) * LOG2E);
    bW = *(const float4*)(b_Wiou + 128 + jb); bU_ = *(const float4*)(b_Uiou + 128 + jb);
    float4 bU = make_float4((bW.x + bU_.x) * LOG2E, (bW.y + bU_.y) * LOG2E, (bW.z + bU_.z) * LOG2E, (bW.w + bU_.w) * LOG2E);
    const float* pbI = &bI.x; const float* pbO = &bO.x; const float* pbU = &bU.x;
#pragma unroll
    for (int t = 0; t < 4; t++) {
        int v = v0 + t * 16 + l15;
        float4 c4; float* pc4 = &c4.x;
        union { bf16 h[4]; uint2 u; } hp;
#pragma unroll
        for (int r = 0; r < 4; r++) {
            float i_g = sig2(acc[t][0][r] + pbI[r]);
            float o_g = sig2(acc[t][1][r] + pbO[r]);
            float u_g = tanhf_(sig2(acc[t][2][r] + pbU[r]));
            float c = i_g * u_g;
            pc4[r] = c;
            hp.h[r] = (bf16)(o_g * tanhf_(c));
        }
        *(float4*)(leafC + (size_t)v * 64 + jb) = c4;
        *(uint2*)(leafH + (size_t)v * 64 + jb) = hp.u;
    }
}

// ---- dispatch 2: levels 16..10. Each block owns the full depth-7 subtree
// under one level-10 node (127 nodes). All intermediate h,c LDS-resident;
// W pinned in VGPRs. waves_per_eu(2,2): max=2 -> 256-VGPR budget, NO SPILL
// (R6 lesson: launch_bounds min-waves alone lets allocator spill pinned W). ----
__attribute__((amdgpu_waves_per_eu(2, 2)))
__global__ void __launch_bounds__(256) subtree_pass(
        const bf16* __restrict__ Wcat, const float* __restrict__ bias,
        const bf16* __restrict__ emb16, const int* __restrict__ token_ids,
        const bf16* __restrict__ leafH, const float* __restrict__ leafC,
        bf16* __restrict__ H, float* __restrict__ c_buf) {
    __shared__ __align__(16) bf16 A0[64 * A_PAD];        // 25600 B
    __shared__ __align__(16) bf16 A1[32 * A_PAD];        // 12800 B
    __shared__ __align__(16) float C0[64 * 68];          // 17408 B
    __shared__ __align__(16) float C1[32 * 68];          //  8704 B  (total 64512)
    const int tid = threadIdx.x, blk = blockIdx.x;
    const int wave = tid >> 6, lane = tid & 63;
    const int l15 = lane & 15, quad = lane >> 4;
    const int jw = wave * 16, jb = jw + quad * 4;

    // stage level-16 tile: x (64 rows) + leaf-children h (64 x 2 halves)
    for (int ch = tid; ch < 64 * 8; ch += 256) {
        int row = ch >> 3, k8 = (ch & 7) << 3;
        int tok = token_ids[65535 + blk * 64 + row];
        *(uint4*)&A0[row * A_PAD + k8] = *(const uint4*)(emb16 + tok * 64 + k8);
    }
    for (int ch = tid; ch < 64 * 16; ch += 256) {
        int row = ch >> 4, half = (ch >> 3) & 1, k8 = (ch & 7) << 3;
        int tok = token_ids[2 * (65535 + blk * 64 + row) + 1 + half];
        *(uint4*)&A0[row * A_PAD + 64 + half * 64 + k8] = *(const uint4*)(leafH + (size_t)tok * 64 + k8);
    }

    // loop-invariant W fragments -> VGPRs, pinned against rematerialization
    f32x4 Wf[5][6];
#pragma unroll
    for (int g = 0; g < 5; g++)
#pragma unroll
        for (int kb = 0; kb < 6; kb++) {
            Wf[g][kb] = *(const f32x4*)(Wcat + (g * 64 + jw + l15) * KDIM + kb * 32 + quad * 8);
            asm volatile("" : "+v"(Wf[g][kb]));
        }

    const float4 bI = *(const float4*)(bias + jb);
    const float4 bO = *(const float4*)(bias + 64 + jb);
    const float4 bU = *(const float4*)(bias + 128 + jb);
    const float4 bL = *(const float4*)(bias + 192 + jb);
    const float4 bR = *(const float4*)(bias + 256 + jb);
    __syncthreads();

    bf16*  Acur = A0; bf16*  Anx = A1;
    float* Cpv  = C0; float* Cnx = C0;     // Cpv unused at l=16
    for (int l = 16; l >= 10; l--) {
        const int m = 1 << (l - 10);
        const int s = (1 << l) - 1, o = blk * m;
        const int T = (m + 15) >> 4;
        for (int ti = 0; ti < T; ti++) {
            int idx0 = ti * 16 + l15;
            int idx = idx0 < m ? idx0 : m - 1;
            int gn = s + o + idx;
            float4 cl, cr;
            if (l == 16) {
                int tkl = token_ids[2 * gn + 1], tkr = token_ids[2 * gn + 2];
                cl = *(const float4*)(leafC + (size_t)tkl * 64 + jb);
                cr = *(const float4*)(leafC + (size_t)tkr * 64 + jb);
            } else {
                cl = *(const float4*)(Cpv + (2 * idx) * 68 + jb);
                cr = *(const float4*)(Cpv + (2 * idx + 1) * 68 + jb);
            }
            f32x4 acc[5];
#pragma unroll
            for (int g = 0; g < 5; g++) acc[g] = (f32x4){0.f, 0.f, 0.f, 0.f};
#pragma unroll
            for (int kb = 0; kb < 6; kb++) {
                bf16x8 nf = *(const bf16x8*)(&Acur[idx * A_PAD + kb * 32 + quad * 8]);
#pragma unroll
                for (int g = 0; g < 5; g++)
                    acc[g] = __builtin_amdgcn_mfma_f32_16x16x32_bf16(as_bf16x8(Wf[g][kb]), nf, acc[g], 0, 0, 0);
            }
            float4 c4, h4;
            gates(acc, bI, bO, bU, bL, bR, cl, cr, c4, h4);
            if (idx0 < m) {
                union { bf16 h[4]; uint2 u; } hp;
                const float* ph4 = &h4.x;
#pragma unroll
                for (int r = 0; r < 4; r++) hp.h[r] = (bf16)ph4[r];
                if (l > 10) {
                    *(float4*)(Cnx + idx * 68 + jb) = c4;
                    *(uint2*)(&Anx[(idx >> 1) * A_PAD + 64 + (idx & 1) * 64 + jb]) = hp.u;
                } else {
                    *(float4*)(c_buf + (size_t)gn * 64 + jb) = c4;
                    *(uint2*)(H + (size_t)gn * 64 + jb) = hp.u;
                }
            }
        }
        if (l > 10) {   // stage next level's x (h-slots filled by epilogue above)
            int mn = m >> 1, sn = (1 << (l - 1)) - 1, on = blk * mn;
            for (int ch = tid; ch < mn * 8; ch += 256) {
                int row = ch >> 3, k8 = (ch & 7) << 3;
                int tok = token_ids[sn + on + row];
                *(uint4*)&Anx[row * A_PAD + k8] = *(const uint4*)(emb16 + tok * 64 + k8);
            }
        }
        __syncthreads();
        bf16* ta = Acur; Acur = Anx; Anx = ta;
        Cpv = Cnx; Cnx = (Cnx == C0) ? C1 : C0;
    }
}

// ---- dispatch 3: levels 9..0, ONE block x 512 thr (8 waves: wj x wt).
// W pinned in VGPRs; waves_per_eu(2,2) -> 256-VGPR budget (8 waves = exactly
// 2/EU for this single block), no spill. h,c via global L2. ----
__attribute__((amdgpu_waves_per_eu(2, 2)))
__global__ void __launch_bounds__(512) tail_pass(
        const bf16* __restrict__ Wcat, const float* __restrict__ bias,
        const bf16* __restrict__ emb16, const int* __restrict__ token_ids,
        bf16* __restrict__ H, float* __restrict__ c_buf, float* __restrict__ out) {
    const int tid = threadIdx.x;
    const int wave = tid >> 6, lane = tid & 63;
    const int l15 = lane & 15, quad = lane >> 4;
    const int wj = wave & 3, wt = wave >> 2;
    const int jw = wj * 16, jb = jw + quad * 4;

    f32x4 Wf[5][6];
#pragma unroll
    for (int g = 0; g < 5; g++)
#pragma unroll
        for (int kb = 0; kb < 6; kb++) {
            Wf[g][kb] = *(const f32x4*)(Wcat + (g * 64 + jw + l15) * KDIM + kb * 32 + quad * 8);
            asm volatile("" : "+v"(Wf[g][kb]));
        }

    const float4 bI = *(const float4*)(bias + jb);
    const float4 bO = *(const float4*)(bias + 64 + jb);
    const float4 bU = *(const float4*)(bias + 128 + jb);
    const float4 bL = *(const float4*)(bias + 192 + jb);
    const float4 bR = *(const float4*)(bias + 256 + jb);

    for (int l = 9; l >= 0; l--) {
        const int n = 1 << l, start = n - 1;
        const int T = (n + 15) >> 4;
        for (int ti = wt; ti < T; ti += 2) {
            int idx0 = ti * 16 + l15;
            int idx = idx0 < n ? idx0 : n - 1;
            int gn = start + idx;
            int tok = token_ids[gn];
            const bf16* hsrc = H + (size_t)(2 * gn + 1) * 64;   // children h, contiguous 256B
            float4 cl = *(const float4*)(c_buf + (size_t)(2 * gn + 1) * 64 + jb);
            float4 cr = *(const float4*)(c_buf + (size_t)(2 * gn + 2) * 64 + jb);
            bf16x8 nf[6];
            nf[0] = *(const bf16x8*)(emb16 + tok * 64 + quad * 8);
            nf[1] = *(const bf16x8*)(emb16 + tok * 64 + 32 + quad * 8);
#pragma unroll
            for (int kb = 2; kb < 6; kb++)
                nf[kb] = *(const bf16x8*)(hsrc + (kb - 2) * 32 + quad * 8);
            f32x4 acc[5];
#pragma unroll
            for (int g = 0; g < 5; g++) acc[g] = (f32x4){0.f, 0.f, 0.f, 0.f};
#pragma unroll
            for (int kb = 0; kb < 6; kb++)
#pragma unroll
                for (int g = 0; g < 5; g++)
                    acc[g] = __builtin_amdgcn_mfma_f32_16x16x32_bf16(as_bf16x8(Wf[g][kb]), nf[kb], acc[g], 0, 0, 0);
            float4 c4, h4;
            gates(acc, bI, bO, bU, bL, bR, cl, cr, c4, h4);
            if (idx0 < n) {
                if (l > 0) {
                    union { bf16 h[4]; uint2 u; } hp;
                    const float* ph4 = &h4.x;
#pragma unroll
                    for (int r = 0; r < 4; r++) hp.h[r] = (bf16)ph4[r];
                    *(float4*)(c_buf + (size_t)gn * 64 + jb) = c4;
                    *(uint2*)(H + (size_t)gn * 64 + jb) = hp.u;
                } else {
                    *(float4*)(out + jb) = h4;        // stack([h, c]): h
                    *(float4*)(out + 64 + jb) = c4;   // c
                }
            }
        }
        __syncthreads();
    }
}

extern "C" void kernel_launch(void* const* d_in, const int* in_sizes, int n_in,
                              void* d_out, int out_size, void* d_ws, size_t ws_size,
                              hipStream_t stream) {
    const int*   token_ids = (const int*)d_in[0];
    const float* emb       = (const float*)d_in[1];
    const float* W_iou     = (const float*)d_in[2];
    const float* b_Wiou    = (const float*)d_in[3];
    const float* U_iou     = (const float*)d_in[4];
    const float* b_Uiou    = (const float*)d_in[5];
    const float* W_f       = (const float*)d_in[6];
    const float* b_Wf      = (const float*)d_in[7];
    const float* U_f       = (const float*)d_in[8];
    const float* b_Uf      = (const float*)d_in[9];
    float* out = (float*)d_out;

    char* ws = (char*)d_ws;
    bf16*  Wcat  = (bf16*)ws;                               // 122880 B
    float* bias  = (float*)(ws + 122880);                   // 1280 B -> 124160
    bf16*  emb16 = (bf16*)(ws + 124160);                    // 262144 B -> 386304
    bf16*  leafH = (bf16*)(ws + 386304);                    // 262144 B -> 648448
    float* leafC = (float*)(ws + 648448);                   // 524288 B -> 1172736
    bf16*  H     = (bf16*)(ws + 1172736);                   // 33554304 B -> 34727040
    float* c_buf = (float*)(ws + 34727040);                 // 67108608 B

    prep_all<<<544, 256, 0, stream>>>(emb, W_iou, U_iou, W_f, U_f,
                                      b_Wiou, b_Uiou, b_Wf, b_Uf,
                                      Wcat, bias, emb16, leafH, leafC);
    subtree_pass<<<1024, 256, 0, stream>>>(Wcat, bias, emb16, token_ids,
                                           leafH, leafC, H, c_buf);
    tail_pass<<<1, 512, 0, stream>>>(Wcat, bias, emb16, token_ids, H, c_buf, out);
}

// Round 8
// 216.208 us; speedup vs baseline: 1.0708x; 1.0708x over previous
//
#include <hip/hip_runtime.h>

typedef __bf16 bf16;
typedef __bf16 bf16x8 __attribute__((ext_vector_type(8)));
typedef float f32x4 __attribute__((ext_vector_type(4)));

#define KDIM    192                     // E + 2H
#define RDIM    320                     // 3H + 2H
#define A_PAD   200                     // padded A-row stride (bf16 elems)
#define LOG2E   1.4426950408889634f

__device__ __forceinline__ float rcpf(float x) { return __builtin_amdgcn_rcpf(x); }
// pre-activations pre-scaled by log2e (folded into Wcat/bias)
__device__ __forceinline__ float sig2(float p)  { return rcpf(1.f + exp2f(-p)); }
__device__ __forceinline__ float tanhf_(float x){ return 2.f * rcpf(1.f + exp2f(-2.f * LOG2E * x)) - 1.f; }

// shared epilogue: acc[5] + biases + children c -> c4, h4
__device__ __forceinline__ void gates(const f32x4* acc,
        const float4& bI, const float4& bO, const float4& bU,
        const float4& bL, const float4& bR,
        const float4& cl, const float4& cr, float4& c4, float4& h4) {
    const float* pbI = &bI.x; const float* pbO = &bO.x; const float* pbU = &bU.x;
    const float* pbL = &bL.x; const float* pbR = &bR.x;
    const float* pcl = &cl.x; const float* pcr = &cr.x;
    float* pc4 = &c4.x; float* ph4 = &h4.x;
#pragma unroll
    for (int r = 0; r < 4; r++) {
        float i_g = sig2(acc[0][r] + pbI[r]);
        float o_g = sig2(acc[1][r] + pbO[r]);
        float u_g = tanhf_(sig2(acc[2][r] + pbU[r]));   // ref: tanh(sigmoid(pre_u))
        float fl  = sig2(acc[3][r] + pbL[r]);
        float fr  = sig2(acc[4][r] + pbR[r]);
        float c = i_g * u_g + fl * pcl[r] + fr * pcr[r];
        pc4[r] = c;
        ph4[r] = o_g * tanhf_(c);
    }
}

// ---- dispatch 1: blocks 0..511 elementwise pack (Wcat, bias, emb16);
// blocks 512..543 leaf tables (independent: convert own W/emb slices). ----
__global__ void prep_all(const float* __restrict__ emb,
                     const float* __restrict__ W_iou, const float* __restrict__ U_iou,
                     const float* __restrict__ W_f,   const float* __restrict__ U_f,
                     const float* __restrict__ b_Wiou, const float* __restrict__ b_Uiou,
                     const float* __restrict__ b_Wf,   const float* __restrict__ b_Uf,
                     bf16* __restrict__ Wcat, float* __restrict__ bias, bf16* __restrict__ emb16,
                     bf16* __restrict__ leafH, float* __restrict__ leafC) {
    __shared__ __align__(16) bf16 Wl[192 * 72];
    __shared__ __align__(16) bf16 Al[64 * 72];
    const int blk = blockIdx.x, tid = threadIdx.x;
    if (blk < 512) {
        int t = blk * 256 + tid;                 // t < 131072 == 2048*64
        emb16[t] = (bf16)emb[t];
        if (t < RDIM * KDIM) {
            int r = t / KDIM, k = t % KDIM;
            float v;
            if (r < 192) v = (k < 64) ? W_iou[r * 64 + k] : U_iou[r * 128 + (k - 64)];
            else { int rr = r - 192; v = (k < 64) ? W_f[rr * 64 + k] : U_f[rr * 128 + (k - 64)]; }
            Wcat[t] = (bf16)(v * LOG2E);
        }
        if (t < RDIM)
            bias[t] = ((t < 192) ? (b_Wiou[t] + b_Uiou[t]) : (b_Wf[t - 192] + b_Uf[t - 192])) * LOG2E;
        return;
    }
    // ---- leaf-table block: vocab slice [v0, v0+64) ----
    const int v0 = (blk - 512) * 64;
    for (int i = tid; i < 192 * 64; i += 256) {
        int r = i >> 6, k = i & 63;
        Wl[r * 72 + k] = (bf16)(W_iou[i] * LOG2E);
    }
    for (int i = tid; i < 64 * 64; i += 256) {
        int r = i >> 6, k = i & 63;
        Al[r * 72 + k] = (bf16)emb[(v0 << 6) + i];
    }
    __syncthreads();
    const int wave = tid >> 6, lane = tid & 63;
    const int l15 = lane & 15, quad = lane >> 4;
    const int jw = (wave & 3) * 16, jb = jw + quad * 4;

    f32x4 acc[4][3];
#pragma unroll
    for (int t = 0; t < 4; t++)
#pragma unroll
        for (int g = 0; g < 3; g++) acc[t][g] = (f32x4){0.f, 0.f, 0.f, 0.f};
#pragma unroll
    for (int kb = 0; kb < 2; kb++) {
        bf16x8 wfrag[3], nfrag[4];
#pragma unroll
        for (int g = 0; g < 3; g++)
            wfrag[g] = *(const bf16x8*)(&Wl[(g * 64 + jw + l15) * 72 + kb * 32 + quad * 8]);
#pragma unroll
        for (int t = 0; t < 4; t++)
            nfrag[t] = *(const bf16x8*)(&Al[(t * 16 + l15) * 72 + kb * 32 + quad * 8]);
#pragma unroll
        for (int t = 0; t < 4; t++)
#pragma unroll
            for (int g = 0; g < 3; g++)
                acc[t][g] = __builtin_amdgcn_mfma_f32_16x16x32_bf16(wfrag[g], nfrag[t], acc[t][g], 0, 0, 0);
    }
    float4 bW, bU_;
    bW = *(const float4*)(b_Wiou + jb);       bU_ = *(const float4*)(b_Uiou + jb);
    float4 bI = make_float4((bW.x + bU_.x) * LOG2E, (bW.y + bU_.y) * LOG2E, (bW.z + bU_.z) * LOG2E, (bW.w + bU_.w) * LOG2E);
    bW = *(const float4*)(b_Wiou + 64 + jb);  bU_ = *(const float4*)(b_Uiou + 64 + jb);
    float4 bO = make_float4((bW.x + bU_.x) * LOG2E, (bW.y + bU_.y) * LOG2E, (bW.z + bU_.z) * LOG2E, (bW.w + bU_.w) * LOG2E);
    bW = *(const float4*)(b_Wiou + 128 + jb); bU_ = *(const float4*)(b_Uiou + 128 + jb);
    float4 bU = make_float4((bW.x + bU_.x) * LOG2E, (bW.y + bU_.y) * LOG2E, (bW.z + bU_.z) * LOG2E, (bW.w + bU_.w) * LOG2E);
    const float* pbI = &bI.x; const float* pbO = &bO.x; const float* pbU = &bU.x;
#pragma unroll
    for (int t = 0; t < 4; t++) {
        int v = v0 + t * 16 + l15;
        float4 c4; float* pc4 = &c4.x;
        union { bf16 h[4]; uint2 u; } hp;
#pragma unroll
        for (int r = 0; r < 4; r++) {
            float i_g = sig2(acc[t][0][r] + pbI[r]);
            float o_g = sig2(acc[t][1][r] + pbO[r]);
            float u_g = tanhf_(sig2(acc[t][2][r] + pbU[r]));
            float c = i_g * u_g;
            pc4[r] = c;
            hp.h[r] = (bf16)(o_g * tanhf_(c));
        }
        *(float4*)(leafC + (size_t)v * 64 + jb) = c4;
        *(uint2*)(leafH + (size_t)v * 64 + jb) = hp.u;
    }
}

// ---- generalized subtree: levels top..top-6, one depth-7 subtree (64 top
// nodes) per rep. W staged ONCE per block into LDS, XOR-swizzled (stride 192
// = 0 mod 32 banks; chunk^(row&7) spreads rows -> 2-way max = free).
// Intermediate h in LDS A-tiles, c via global L2 (same-block: barrier only).
// leafMode: children of top level come from leafH/leafC tables. ----
__global__ __launch_bounds__(256) void subtree_pass(
        const bf16* __restrict__ Wcat, const float* __restrict__ bias,
        const bf16* __restrict__ emb16, const int* __restrict__ token_ids,
        const bf16* __restrict__ leafH, const float* __restrict__ leafC,
        bf16* __restrict__ H, float* __restrict__ c_buf,
        int top, int leafMode, int reps) {
    __shared__ __align__(16) bf16 Wl[RDIM * KDIM];   // 122880 B, swizzled
    __shared__ __align__(16) bf16 A0[64 * A_PAD];    // 25600 B
    __shared__ __align__(16) bf16 A1[32 * A_PAD];    // 12800 B  (total 161280)
    const int tid = threadIdx.x, blk = blockIdx.x;
    const int wave = tid >> 6, lane = tid & 63;
    const int l15 = lane & 15, quad = lane >> 4;
    const int jw = wave * 16, jb = jw + quad * 4;
    const int swz = l15 & 7;
    const int bot = top - 6;
    const int stop = (1 << top) - 1;

    // stage Wcat -> LDS once (7680 x 16B chunks, swizzled position)
    for (int ch = tid; ch < 7680; ch += 256) {
        int wr = ch / 24, c = ch - wr * 24;
        *(uint4*)&Wl[wr * KDIM + ((c ^ (wr & 7)) << 3)] =
            *(const uint4*)(Wcat + wr * KDIM + (c << 3));
    }

    const float4 bI = *(const float4*)(bias + jb);
    const float4 bO = *(const float4*)(bias + 64 + jb);
    const float4 bU = *(const float4*)(bias + 128 + jb);
    const float4 bL = *(const float4*)(bias + 192 + jb);
    const float4 bR = *(const float4*)(bias + 256 + jb);

    for (int rep = 0; rep < reps; rep++) {
        const int sub = blk * reps + rep;
        // stage top-level tile: x (64 rows) + children h
        for (int ch = tid; ch < 64 * 8; ch += 256) {
            int row = ch >> 3, k8 = (ch & 7) << 3;
            int tok = token_ids[stop + sub * 64 + row];
            *(uint4*)&A0[row * A_PAD + k8] = *(const uint4*)(emb16 + tok * 64 + k8);
        }
        if (leafMode) {
            for (int ch = tid; ch < 64 * 16; ch += 256) {
                int row = ch >> 4, half = (ch >> 3) & 1, k8 = (ch & 7) << 3;
                int tok = token_ids[2 * (stop + sub * 64 + row) + 1 + half];
                *(uint4*)&A0[row * A_PAD + 64 + half * 64 + k8] =
                    *(const uint4*)(leafH + (size_t)tok * 64 + k8);
            }
        } else {
            for (int ch = tid; ch < 64 * 16; ch += 256) {
                int row = ch >> 4, k8 = (ch & 15) << 3;
                int gnc = stop + sub * 64 + row;
                *(uint4*)&A0[row * A_PAD + 64 + k8] =
                    *(const uint4*)(H + (size_t)(2 * gnc + 1) * 64 + k8);
            }
        }
        __syncthreads();   // W (rep 0) + A0 ready

        bf16* Acur = A0; bf16* Anx = A1;
        for (int l = top; l >= bot; l--) {
            const int m = 1 << (l - bot);
            const int s = (1 << l) - 1, o = sub * m;
            const int T = (m + 15) >> 4;
            for (int ti = 0; ti < T; ti++) {
                int idx0 = ti * 16 + l15;
                int idx = idx0 < m ? idx0 : m - 1;
                int gn = s + o + idx;
                float4 cl, cr;
                if (l == top && leafMode) {
                    int tkl = token_ids[2 * gn + 1], tkr = token_ids[2 * gn + 2];
                    cl = *(const float4*)(leafC + (size_t)tkl * 64 + jb);
                    cr = *(const float4*)(leafC + (size_t)tkr * 64 + jb);
                } else {
                    cl = *(const float4*)(c_buf + (size_t)(2 * gn + 1) * 64 + jb);
                    cr = *(const float4*)(c_buf + (size_t)(2 * gn + 2) * 64 + jb);
                }
                f32x4 acc[5];
#pragma unroll
                for (int g = 0; g < 5; g++) acc[g] = (f32x4){0.f, 0.f, 0.f, 0.f};
#pragma unroll
                for (int kb = 0; kb < 6; kb++) {
                    bf16x8 nf = *(const bf16x8*)(&Acur[idx * A_PAD + kb * 32 + quad * 8]);
#pragma unroll
                    for (int g = 0; g < 5; g++) {
                        bf16x8 wf = *(const bf16x8*)(&Wl[(g * 64 + jw + l15) * KDIM
                                        + ((((kb << 2) + quad) ^ swz) << 3)]);
                        acc[g] = __builtin_amdgcn_mfma_f32_16x16x32_bf16(wf, nf, acc[g], 0, 0, 0);
                    }
                }
                float4 c4, h4;
                gates(acc, bI, bO, bU, bL, bR, cl, cr, c4, h4);
                if (idx0 < m) {
                    union { bf16 h[4]; uint2 u; } hp;
                    const float* ph4 = &h4.x;
#pragma unroll
                    for (int r = 0; r < 4; r++) hp.h[r] = (bf16)ph4[r];
                    *(float4*)(c_buf + (size_t)gn * 64 + jb) = c4;
                    if (l > bot)
                        *(uint2*)(&Anx[(idx >> 1) * A_PAD + 64 + (idx & 1) * 64 + jb]) = hp.u;
                    else
                        *(uint2*)(H + (size_t)gn * 64 + jb) = hp.u;
                }
            }
            if (l > bot) {   // stage next level's x (h-slots filled by epilogue)
                int mn = m >> 1, sn = (1 << (l - 1)) - 1, on = sub * mn;
                for (int ch = tid; ch < mn * 8; ch += 256) {
                    int row = ch >> 3, k8 = (ch & 7) << 3;
                    int tok = token_ids[sn + on + row];
                    *(uint4*)&Anx[row * A_PAD + k8] = *(const uint4*)(emb16 + tok * 64 + k8);
                }
            }
            __syncthreads();
            bf16* ta = Acur; Acur = Anx; Anx = ta;
        }
    }
}

// ---- dispatch 4: levels 2..0 (7 nodes), 1 block x 256 thr. Tiny: W straight
// from L2 per tile; h,c via global L2 (same-block barrier visibility). ----
__global__ __launch_bounds__(256) void tail3(
        const bf16* __restrict__ Wcat, const float* __restrict__ bias,
        const bf16* __restrict__ emb16, const int* __restrict__ token_ids,
        bf16* __restrict__ H, float* __restrict__ c_buf, float* __restrict__ out) {
    const int tid = threadIdx.x;
    const int wave = tid >> 6, lane = tid & 63;
    const int l15 = lane & 15, quad = lane >> 4;
    const int jw = wave * 16, jb = jw + quad * 4;
    const float4 bI = *(const float4*)(bias + jb);
    const float4 bO = *(const float4*)(bias + 64 + jb);
    const float4 bU = *(const float4*)(bias + 128 + jb);
    const float4 bL = *(const float4*)(bias + 192 + jb);
    const float4 bR = *(const float4*)(bias + 256 + jb);

    for (int l = 2; l >= 0; l--) {
        const int n = 1 << l, start = n - 1;
        int idx = l15 < n ? l15 : n - 1;
        int gn = start + idx;
        int tok = token_ids[gn];
        const bf16* hsrc = H + (size_t)(2 * gn + 1) * 64;
        float4 cl = *(const float4*)(c_buf + (size_t)(2 * gn + 1) * 64 + jb);
        float4 cr = *(const float4*)(c_buf + (size_t)(2 * gn + 2) * 64 + jb);
        bf16x8 nf[6];
        nf[0] = *(const bf16x8*)(emb16 + tok * 64 + quad * 8);
        nf[1] = *(const bf16x8*)(emb16 + tok * 64 + 32 + quad * 8);
#pragma unroll
        for (int kb = 2; kb < 6; kb++)
            nf[kb] = *(const bf16x8*)(hsrc + (kb - 2) * 32 + quad * 8);
        f32x4 acc[5];
#pragma unroll
        for (int g = 0; g < 5; g++) acc[g] = (f32x4){0.f, 0.f, 0.f, 0.f};
#pragma unroll
        for (int kb = 0; kb < 6; kb++)
#pragma unroll
            for (int g = 0; g < 5; g++) {
                bf16x8 wf = *(const bf16x8*)(Wcat + (g * 64 + jw + l15) * KDIM + kb * 32 + quad * 8);
                acc[g] = __builtin_amdgcn_mfma_f32_16x16x32_bf16(wf, nf[kb], acc[g], 0, 0, 0);
            }
        float4 c4, h4;
        gates(acc, bI, bO, bU, bL, bR, cl, cr, c4, h4);
        if (l15 < n) {
            if (l > 0) {
                union { bf16 h[4]; uint2 u; } hp;
                const float* ph4 = &h4.x;
#pragma unroll
                for (int r = 0; r < 4; r++) hp.h[r] = (bf16)ph4[r];
                *(float4*)(c_buf + (size_t)gn * 64 + jb) = c4;
                *(uint2*)(H + (size_t)gn * 64 + jb) = hp.u;
            } else {
                *(float4*)(out + jb) = h4;        // stack([h, c]): h
                *(float4*)(out + 64 + jb) = c4;   // c
            }
        }
        __syncthreads();
    }
}

extern "C" void kernel_launch(void* const* d_in, const int* in_sizes, int n_in,
                              void* d_out, int out_size, void* d_ws, size_t ws_size,
                              hipStream_t stream) {
    const int*   token_ids = (const int*)d_in[0];
    const float* emb       = (const float*)d_in[1];
    const float* W_iou     = (const float*)d_in[2];
    const float* b_Wiou    = (const float*)d_in[3];
    const float* U_iou     = (const float*)d_in[4];
    const float* b_Uiou    = (const float*)d_in[5];
    const float* W_f       = (const float*)d_in[6];
    const float* b_Wf      = (const float*)d_in[7];
    const float* U_f       = (const float*)d_in[8];
    const float* b_Uf      = (const float*)d_in[9];
    float* out = (float*)d_out;

    char* ws = (char*)d_ws;
    bf16*  Wcat  = (bf16*)ws;                               // 122880 B
    float* bias  = (float*)(ws + 122880);                   // 1280 B -> 124160
    bf16*  emb16 = (bf16*)(ws + 124160);                    // 262144 B -> 386304
    bf16*  leafH = (bf16*)(ws + 386304);                    // 262144 B -> 648448
    float* leafC = (float*)(ws + 648448);                   // 524288 B -> 1172736
    bf16*  H     = (bf16*)(ws + 1172736);                   // 33554304 B -> 34727040
    float* c_buf = (float*)(ws + 34727040);                 // 67108608 B

    prep_all<<<544, 256, 0, stream>>>(emb, W_iou, U_iou, W_f, U_f,
                                      b_Wiou, b_Uiou, b_Wf, b_Uf,
                                      Wcat, bias, emb16, leafH, leafC);
    // levels 16..10: 1024 subtrees, 256 blocks x 4 reps (W staged once/block)
    subtree_pass<<<256, 256, 0, stream>>>(Wcat, bias, emb16, token_ids,
                                          leafH, leafC, H, c_buf, 16, 1, 4);
    // levels 9..3: 8 subtrees
    subtree_pass<<<8, 256, 0, stream>>>(Wcat, bias, emb16, token_ids,
                                        leafH, leafC, H, c_buf, 9, 0, 1);
    // levels 2..0
    tail3<<<1, 256, 0, stream>>>(Wcat, bias, emb16, token_ids, H, c_buf, out);
}